// Round 4
// baseline (157.070 us; speedup 1.0000x reference)
//
#include <hip/hip_runtime.h>

// BS=32, N_IND=8 -> 256 independent problems; N_STEP=100, ORDER=2 (3x3 blocks).
// AtA block-tridiagonal (verified R1). Block cyclic reduction (verified R2/R3).
// R4: MEASUREMENT PROBE — identical kernel launched 8x back-to-back (idempotent:
// reads only inputs, writes same outputs). dur = overhead + 8*k; with R3's
// overhead + k = 70.4 us this solves for both the kernel time k and the
// harness floor, and puts our kernel's dispatches into the rocprof top-5.
#define NPROB 256
#define NSTEP 100
#define T1    99

__global__ __launch_bounds__(64) void ode_cr_kernel(
    const float* __restrict__ coeffs,  // [256][100][3]
    const float* __restrict__ rhs,     // [256][100]
    const float* __restrict__ iv_rhs,  // [256][2]
    const float* __restrict__ steps,   // [256][99]
    float* __restrict__ out)           // u0[25600] u1[25600] u2[25600] eps[256] st[25344]
{
    const int b   = blockIdx.x;
    const int tid = threadIdx.x;

    __shared__ double A[NSTEP][6];   // diag block, sym: a00,a01,a02,a11,a12,a22
    __shared__ double C[NSTEP][9];   // sub-diag block: row t -> col t-stride, row-major
    __shared__ double bb[NSTEP][3];  // rhs
    __shared__ double P[NSTEP][9];   // G_t * C_t
    __shared__ double Q[NSTEP][9];   // G_t * C_{t+stride}^T
    __shared__ double z[NSTEP][3];   // G_t * b_t
    __shared__ double X[NSTEP][3];   // solution

    const float* cb = coeffs + b * NSTEP * 3;
    const float* rb = rhs    + b * NSTEP;
    const float* sb = steps  + b * T1;

    // ---------------- build blocks (2 iterations of 64 lanes) ----------------
    for (int t = tid; t < NSTEP; t += 64) {
        const double c0 = (double)cb[t * 3 + 0];
        const double c1 = (double)cb[t * 3 + 1];
        const double c2 = (double)cb[t * 3 + 2];
        const double r  = (double)rb[t];

        double a00 = c0 * c0, a01 = c0 * c1, a02 = c0 * c2;
        double a11 = c1 * c1, a12 = c1 * c2, a22 = c2 * c2;
        double b0 = c0 * r, b1 = c1 * r, b2 = c2 * r;

        if (t == 0) {
            a00 += 1.0; a11 += 1.0;
            b0 += (double)iv_rhs[b * 2 + 0];
            b1 += (double)iv_rhs[b * 2 + 1];
        }
        if (t < T1) {  // U(h_t)
            const double h = (double)sb[t], h2 = h * h;
            a00 += 2.0;
            a01 += h;
            a02 += 0.5 * h2;
            a11 += h2 + 3.0;
            a12 += 0.5 * h2 * h + 1.5 * h;
            a22 += 0.25 * h2 * h2 + 1.25 * h2;
        }
        if (t > 0) {   // V(h_{t-1}) and coupling E(h_{t-1})
            const double hm = (double)sb[t - 1], hm2 = hm * hm;
            a00 += 2.0;
            a01 -= hm;
            a02 += 0.5 * hm2;
            a11 += hm2 + 3.0;
            a12 -= 0.5 * hm2 * hm + 1.5 * hm;
            a22 += 0.25 * hm2 * hm2 + 1.25 * hm2;

            C[t][0] = -2.0;       C[t][1] = -hm;       C[t][2] = -0.5 * hm2;
            C[t][3] =  hm;        C[t][4] = -3.0;      C[t][5] = -1.5 * hm;
            C[t][6] = -0.5 * hm2; C[t][7] =  1.5 * hm; C[t][8] =  0.25 * hm2;
        }
        A[t][0] = a00; A[t][1] = a01; A[t][2] = a02;
        A[t][3] = a11; A[t][4] = a12; A[t][5] = a22;
        bb[t][0] = b0; bb[t][1] = b1; bb[t][2] = b2;
    }
    __syncthreads();

    // level sizes are compile-time: 100,50,25,13,7,4,2 (then 1 = root)
    const int NC[7] = {100, 50, 25, 13, 7, 4, 2};

    // ---------------- down-sweep ----------------
#pragma unroll
    for (int lev = 0; lev < 7; ++lev) {
        const int n = NC[lev];
        const int stride = 1 << lev;

        // odd phase: G = A^-1 via adjugate (1 fp64 div), P/Q/z = G * {...}
        int j = 2 * tid + 1;
        if (j < n) {
            const int t = j * stride;
            const double a00 = A[t][0], a01 = A[t][1], a02 = A[t][2];
            const double a11 = A[t][3], a12 = A[t][4], a22 = A[t][5];
            const double k00 = a11 * a22 - a12 * a12;
            const double k01 = a02 * a12 - a01 * a22;
            const double k02 = a01 * a12 - a02 * a11;
            const double det = a00 * k00 + a01 * k01 + a02 * k02;
            const double id  = 1.0 / det;
            const double g00 = k00 * id;
            const double g01 = k01 * id;
            const double g02 = k02 * id;
            const double g11 = (a00 * a22 - a02 * a02) * id;
            const double g12 = (a02 * a01 - a00 * a12) * id;
            const double g22 = (a00 * a11 - a01 * a01) * id;

            // P = G * C[t]   (C row-major)
#pragma unroll
            for (int k = 0; k < 3; ++k) {
                const double c0k = C[t][k], c1k = C[t][3 + k], c2k = C[t][6 + k];
                P[t][k]     = g00 * c0k + g01 * c1k + g02 * c2k;
                P[t][3 + k] = g01 * c0k + g11 * c1k + g12 * c2k;
                P[t][6 + k] = g02 * c0k + g12 * c1k + g22 * c2k;
            }
            if (j + 1 < n) {  // Q = G * C[t+stride]^T
                const int tr = t + stride;
#pragma unroll
                for (int k = 0; k < 3; ++k) {
                    const double cr0 = C[tr][3 * k], cr1 = C[tr][3 * k + 1], cr2 = C[tr][3 * k + 2];
                    Q[t][k]     = g00 * cr0 + g01 * cr1 + g02 * cr2;
                    Q[t][3 + k] = g01 * cr0 + g11 * cr1 + g12 * cr2;
                    Q[t][6 + k] = g02 * cr0 + g12 * cr1 + g22 * cr2;
                }
            }
            const double b0 = bb[t][0], b1 = bb[t][1], b2 = bb[t][2];
            z[t][0] = g00 * b0 + g01 * b1 + g02 * b2;
            z[t][1] = g01 * b0 + g11 * b1 + g12 * b2;
            z[t][2] = g02 * b0 + g12 * b1 + g22 * b2;
        }
        __syncthreads();

        // even phase: Schur-update survivors
        j = 2 * tid;
        if (j < n) {
            const int t = j * stride;
            double a00 = A[t][0], a01 = A[t][1], a02 = A[t][2];
            double a11 = A[t][3], a12 = A[t][4], a22 = A[t][5];
            double b0 = bb[t][0], b1 = bb[t][1], b2 = bb[t][2];
            double nc[9];
            const bool hasL = (j > 0);
            if (hasL) {
                const int ti = t - stride;
                double Ct[9];
#pragma unroll
                for (int k = 0; k < 9; ++k) Ct[k] = C[t][k];
                const double* Qi = Q[ti];
                a00 -= Ct[0] * Qi[0] + Ct[1] * Qi[3] + Ct[2] * Qi[6];
                a01 -= Ct[0] * Qi[1] + Ct[1] * Qi[4] + Ct[2] * Qi[7];
                a02 -= Ct[0] * Qi[2] + Ct[1] * Qi[5] + Ct[2] * Qi[8];
                a11 -= Ct[3] * Qi[1] + Ct[4] * Qi[4] + Ct[5] * Qi[7];
                a12 -= Ct[3] * Qi[2] + Ct[4] * Qi[5] + Ct[5] * Qi[8];
                a22 -= Ct[6] * Qi[2] + Ct[7] * Qi[5] + Ct[8] * Qi[8];
                const double* Pi = P[ti];
#pragma unroll
                for (int r0 = 0; r0 < 3; ++r0)
#pragma unroll
                    for (int c0 = 0; c0 < 3; ++c0)
                        nc[3 * r0 + c0] = -(Ct[3 * r0] * Pi[c0] +
                                            Ct[3 * r0 + 1] * Pi[3 + c0] +
                                            Ct[3 * r0 + 2] * Pi[6 + c0]);
                const double* zi = z[ti];
                b0 -= Ct[0] * zi[0] + Ct[1] * zi[1] + Ct[2] * zi[2];
                b1 -= Ct[3] * zi[0] + Ct[4] * zi[1] + Ct[5] * zi[2];
                b2 -= Ct[6] * zi[0] + Ct[7] * zi[1] + Ct[8] * zi[2];
            }
            if (j + 1 < n) {
                const int ti = t + stride;
                double Cr[9];
#pragma unroll
                for (int k = 0; k < 9; ++k) Cr[k] = C[ti][k];
                const double* Pi = P[ti];
                a00 -= Cr[0] * Pi[0] + Cr[3] * Pi[3] + Cr[6] * Pi[6];
                a01 -= Cr[0] * Pi[1] + Cr[3] * Pi[4] + Cr[6] * Pi[7];
                a02 -= Cr[0] * Pi[2] + Cr[3] * Pi[5] + Cr[6] * Pi[8];
                a11 -= Cr[1] * Pi[1] + Cr[4] * Pi[4] + Cr[7] * Pi[7];
                a12 -= Cr[1] * Pi[2] + Cr[4] * Pi[5] + Cr[7] * Pi[8];
                a22 -= Cr[2] * Pi[2] + Cr[5] * Pi[5] + Cr[8] * Pi[8];
                const double* zi = z[ti];
                b0 -= Cr[0] * zi[0] + Cr[3] * zi[1] + Cr[6] * zi[2];
                b1 -= Cr[1] * zi[0] + Cr[4] * zi[1] + Cr[7] * zi[2];
                b2 -= Cr[2] * zi[0] + Cr[5] * zi[1] + Cr[8] * zi[2];
            }
            A[t][0] = a00; A[t][1] = a01; A[t][2] = a02;
            A[t][3] = a11; A[t][4] = a12; A[t][5] = a22;
            bb[t][0] = b0; bb[t][1] = b1; bb[t][2] = b2;
            if (hasL)
#pragma unroll
                for (int k = 0; k < 9; ++k) C[t][k] = nc[k];
        }
        __syncthreads();
    }

    // ---------------- root solve: X_0 = A_0^-1 b_0 ----------------
    if (tid == 0) {
        const double a00 = A[0][0], a01 = A[0][1], a02 = A[0][2];
        const double a11 = A[0][3], a12 = A[0][4], a22 = A[0][5];
        const double k00 = a11 * a22 - a12 * a12;
        const double k01 = a02 * a12 - a01 * a22;
        const double k02 = a01 * a12 - a02 * a11;
        const double det = a00 * k00 + a01 * k01 + a02 * k02;
        const double id  = 1.0 / det;
        const double g00 = k00 * id;
        const double g01 = k01 * id;
        const double g02 = k02 * id;
        const double g11 = (a00 * a22 - a02 * a02) * id;
        const double g12 = (a02 * a01 - a00 * a12) * id;
        const double g22 = (a00 * a11 - a01 * a01) * id;
        const double b0 = bb[0][0], b1 = bb[0][1], b2 = bb[0][2];
        X[0][0] = g00 * b0 + g01 * b1 + g02 * b2;
        X[0][1] = g01 * b0 + g11 * b1 + g12 * b2;
        X[0][2] = g02 * b0 + g12 * b1 + g22 * b2;
    }
    __syncthreads();

    // ---------------- up-sweep: x_t = z_t - P_t x_{t-s} - Q_t x_{t+s} ----------------
#pragma unroll
    for (int lev = 6; lev >= 0; --lev) {
        const int n = NC[lev];
        const int stride = 1 << lev;
        const int j = 2 * tid + 1;
        if (j < n) {
            const int t = j * stride;
            const double* xl = X[t - stride];
            double v0 = z[t][0], v1 = z[t][1], v2 = z[t][2];
            v0 -= P[t][0] * xl[0] + P[t][1] * xl[1] + P[t][2] * xl[2];
            v1 -= P[t][3] * xl[0] + P[t][4] * xl[1] + P[t][5] * xl[2];
            v2 -= P[t][6] * xl[0] + P[t][7] * xl[1] + P[t][8] * xl[2];
            if (j + 1 < n) {
                const double* xr = X[t + stride];
                v0 -= Q[t][0] * xr[0] + Q[t][1] * xr[1] + Q[t][2] * xr[2];
                v1 -= Q[t][3] * xr[0] + Q[t][4] * xr[1] + Q[t][5] * xr[2];
                v2 -= Q[t][6] * xr[0] + Q[t][7] * xr[1] + Q[t][8] * xr[2];
            }
            X[t][0] = v0; X[t][1] = v1; X[t][2] = v2;
        }
        __syncthreads();
    }

    // ---------------- outputs ----------------
    for (int t = tid; t < NSTEP; t += 64) {
        out[            b * NSTEP + t] = (float)X[t][0];  // u0
        out[25600 +     b * NSTEP + t] = (float)X[t][1];  // u1
        out[51200 +     b * NSTEP + t] = (float)X[t][2];  // u2
        if (t < T1)
            out[77056 + b * T1 + t] = sb[t];              // st copy
    }
    if (tid == 0)
        out[76800 + b] = 0.0f;                            // eps
}

extern "C" void kernel_launch(void* const* d_in, const int* in_sizes, int n_in,
                              void* d_out, int out_size, void* d_ws, size_t ws_size,
                              hipStream_t stream) {
    const float* coeffs = (const float*)d_in[0];
    const float* rhs    = (const float*)d_in[1];
    const float* iv_rhs = (const float*)d_in[2];
    const float* steps  = (const float*)d_in[3];
    float* out = (float*)d_out;

    // 8 idempotent replays: dur = harness_overhead + 8*kernel_time.
    // With R3's (overhead + 1*kernel_time) = 70.4 us this solves both.
    for (int i = 0; i < 8; ++i)
        ode_cr_kernel<<<dim3(NPROB), dim3(64), 0, stream>>>(
            coeffs, rhs, iv_rhs, steps, out);
}

// Round 5
// 66.893 us; speedup vs baseline: 2.3481x; 2.3481x over previous
//
#include <hip/hip_runtime.h>

// BS=32, N_IND=8 -> 256 problems; N_STEP=100, ORDER=2 -> 3x3 block-tridiagonal
// normal equations (verified R1, absmax 0.0). R2/R3: LDS cyclic reduction,
// kernel ~12.4 us (R4 probe: harness floor ~58 us). R5: hybrid CR(1)+PCR —
// one CR pre-step folds 100 rows -> 50 (one row/lane), then 6 PCR levels with
// row state (A,C,B,b) in REGISTERS and only P,Q,z (21 doubles) through LDS.
// No up-sweep; odd rows recovered from saved P,Q,z. ~9 compute phases vs 23.
#define NPROB 256
#define NSTEP 100
#define T1    99

// A: symmetric 3x3 as [a00,a01,a02,a11,a12,a22]; C,B: row-major 3x3.
__device__ __forceinline__ void syminv3(const double A[6], double G[6]) {
    const double k00 = A[3] * A[5] - A[4] * A[4];
    const double k01 = A[2] * A[4] - A[1] * A[5];
    const double k02 = A[1] * A[4] - A[2] * A[3];
    const double det = A[0] * k00 + A[1] * k01 + A[2] * k02;
    const double id  = 1.0 / det;
    G[0] = k00 * id;
    G[1] = k01 * id;
    G[2] = k02 * id;
    G[3] = (A[0] * A[5] - A[2] * A[2]) * id;
    G[4] = (A[2] * A[1] - A[0] * A[4]) * id;
    G[5] = (A[0] * A[3] - A[1] * A[1]) * id;
}

// R = Gsym * M (full 3x3)
__device__ __forceinline__ void symmul(const double G[6], const double M[9], double R[9]) {
#pragma unroll
    for (int c = 0; c < 3; ++c) {
        R[0 + c] = G[0] * M[c] + G[1] * M[3 + c] + G[2] * M[6 + c];
        R[3 + c] = G[1] * M[c] + G[3] * M[3 + c] + G[4] * M[6 + c];
        R[6 + c] = G[2] * M[c] + G[4] * M[3 + c] + G[5] * M[6 + c];
    }
}

__device__ __forceinline__ void symvec(const double G[6], const double v[3], double r[3]) {
    r[0] = G[0] * v[0] + G[1] * v[1] + G[2] * v[2];
    r[1] = G[1] * v[0] + G[3] * v[1] + G[4] * v[2];
    r[2] = G[2] * v[0] + G[4] * v[1] + G[5] * v[2];
}

// P = A^-1 C, Q = A^-1 B, z = A^-1 b
__device__ __forceinline__ void pqz(const double A[6], const double C[9],
                                    const double B[9], const double b[3],
                                    double P[9], double Q[9], double z[3]) {
    double G[6];
    syminv3(A, G);
    symmul(G, C, P);
    symmul(G, B, Q);
    symvec(G, b, z);
}

__device__ __forceinline__ void store21(double* dst, const double P[9],
                                        const double Q[9], const double z[3]) {
#pragma unroll
    for (int k = 0; k < 9; ++k) { dst[k] = P[k]; dst[9 + k] = Q[k]; }
#pragma unroll
    for (int k = 0; k < 3; ++k) dst[18 + k] = z[k];
}

// PCR row update: row i, left neighbor data SL = (P,Q,z)_{i-s}, right SR = (P,Q,z)_{i+s}
//   A' = A - C*Q_l - B*P_r ; C' = -C*P_l ; B' = -B*Q_r ; b' = b - C*z_l - B*z_r
__device__ __forceinline__ void upd(double A[6], double C[9], double B[9], double b[3],
                                    const double* SL, const double* SR) {
    double Pl[9], Ql[9], zl[3], Pr[9], Qr[9], zr[3];
#pragma unroll
    for (int k = 0; k < 9; ++k) { Pl[k] = SL[k]; Ql[k] = SL[9 + k]; }
#pragma unroll
    for (int k = 0; k < 3; ++k) zl[k] = SL[18 + k];
#pragma unroll
    for (int k = 0; k < 9; ++k) { Pr[k] = SR[k]; Qr[k] = SR[9 + k]; }
#pragma unroll
    for (int k = 0; k < 3; ++k) zr[k] = SR[18 + k];

    // symmetric entries of A: (0,0),(0,1),(0,2),(1,1),(1,2),(2,2)
    const int RI[6] = {0, 0, 0, 1, 1, 2};
    const int CI[6] = {0, 1, 2, 1, 2, 2};
#pragma unroll
    for (int e = 0; e < 6; ++e) {
        const int r = RI[e], c = CI[e];
        A[e] -= C[3 * r] * Ql[c] + C[3 * r + 1] * Ql[3 + c] + C[3 * r + 2] * Ql[6 + c]
              + B[3 * r] * Pr[c] + B[3 * r + 1] * Pr[3 + c] + B[3 * r + 2] * Pr[6 + c];
    }
    double nC[9], nB[9];
#pragma unroll
    for (int r = 0; r < 3; ++r)
#pragma unroll
        for (int c = 0; c < 3; ++c) {
            nC[3 * r + c] = -(C[3 * r] * Pl[c] + C[3 * r + 1] * Pl[3 + c] + C[3 * r + 2] * Pl[6 + c]);
            nB[3 * r + c] = -(B[3 * r] * Qr[c] + B[3 * r + 1] * Qr[3 + c] + B[3 * r + 2] * Qr[6 + c]);
        }
#pragma unroll
    for (int r = 0; r < 3; ++r)
        b[r] -= C[3 * r] * zl[0] + C[3 * r + 1] * zl[1] + C[3 * r + 2] * zl[2]
              + B[3 * r] * zr[0] + B[3 * r + 1] * zr[1] + B[3 * r + 2] * zr[2];
#pragma unroll
    for (int k = 0; k < 9; ++k) { C[k] = nC[k]; B[k] = nB[k]; }
}

// Build block-row t: A (sym6), C = E(h_{t-1}) (t>0), B = E(h_t)^T (t<99), rhs b.
__device__ __forceinline__ void build_row(int t, const float* cb, const float* rb,
                                          const float* sb, const float* ivp,
                                          double A[6], double C[9], double B[9], double b[3]) {
    const double c0 = (double)cb[t * 3 + 0];
    const double c1 = (double)cb[t * 3 + 1];
    const double c2 = (double)cb[t * 3 + 2];
    const double r  = (double)rb[t];
    A[0] = c0 * c0; A[1] = c0 * c1; A[2] = c0 * c2;
    A[3] = c1 * c1; A[4] = c1 * c2; A[5] = c2 * c2;
    b[0] = c0 * r;  b[1] = c1 * r;  b[2] = c2 * r;
#pragma unroll
    for (int k = 0; k < 9; ++k) { C[k] = 0.0; B[k] = 0.0; }

    if (t == 0) {
        A[0] += 1.0; A[3] += 1.0;
        b[0] += (double)ivp[0];
        b[1] += (double)ivp[1];
    }
    if (t < T1) {  // U(h_t); B = E(h_t)^T
        const double h = (double)sb[t], h2 = h * h;
        A[0] += 2.0;
        A[1] += h;
        A[2] += 0.5 * h2;
        A[3] += h2 + 3.0;
        A[4] += 0.5 * h2 * h + 1.5 * h;
        A[5] += 0.25 * h2 * h2 + 1.25 * h2;
        B[0] = -2.0;       B[1] =  h;         B[2] = -0.5 * h2;
        B[3] = -h;         B[4] = -3.0;       B[5] =  1.5 * h;
        B[6] = -0.5 * h2;  B[7] = -1.5 * h;   B[8] =  0.25 * h2;
    }
    if (t > 0) {   // V(h_{t-1}); C = E(h_{t-1})
        const double hm = (double)sb[t - 1], hm2 = hm * hm;
        A[0] += 2.0;
        A[1] -= hm;
        A[2] += 0.5 * hm2;
        A[3] += hm2 + 3.0;
        A[4] -= 0.5 * hm2 * hm + 1.5 * hm;
        A[5] += 0.25 * hm2 * hm2 + 1.25 * hm2;
        C[0] = -2.0;       C[1] = -hm;        C[2] = -0.5 * hm2;
        C[3] =  hm;        C[4] = -3.0;       C[5] = -1.5 * hm;
        C[6] = -0.5 * hm2; C[7] =  1.5 * hm;  C[8] =  0.25 * hm2;
    }
}

__global__ __launch_bounds__(64, 1) void ode_pcr_kernel(
    const float* __restrict__ coeffs,  // [256][100][3]
    const float* __restrict__ rhs,     // [256][100]
    const float* __restrict__ iv_rhs,  // [256][2]
    const float* __restrict__ steps,   // [256][99]
    float* __restrict__ out)           // u0[25600] u1[25600] u2[25600] eps[256] st[25344]
{
    const int b = blockIdx.x;
    const int L = threadIdx.x;

    // 50-row system slots: pads [0,32) and [82,114) stay zero.
    // Row stride 21 doubles = 42 dwords; gcd(42,32)=2 -> 2-way bank alias (free).
    __shared__ double S[114][21];
    __shared__ double X[52][3];

    for (int i = L; i < 114 * 21; i += 64) ((double*)S)[i] = 0.0;
    for (int i = L; i < 52 * 3;  i += 64) ((double*)X)[i] = 0.0;

    const float* cb  = coeffs + b * NSTEP * 3;
    const float* rb  = rhs    + b * NSTEP;
    const float* sb  = steps  + b * T1;
    const float* ivp = iv_rhs + b * 2;

    const bool act = (L < 50);
    double Ae[6], Ce[9], Be[9], be[3];  // even row 2L (the 50-row system state)
    double Po[9], Qo[9], zo[3];         // odd row 2L+1 publish data (kept for recovery)

    __syncthreads();  // pad zeros visible

    // ---------- build + CR pre-step: publish odd rows ----------
    if (act) {
        build_row(2 * L, cb, rb, sb, ivp, Ae, Ce, Be, be);
        double Ao[6], Co[9], Bo[9], bo[3];
        build_row(2 * L + 1, cb, rb, sb, ivp, Ao, Co, Bo, bo);
        pqz(Ao, Co, Bo, bo, Po, Qo, zo);
        store21(&S[L + 32][0], Po, Qo, zo);
    }
    __syncthreads();
    // even update: odd-left = slot L-1, odd-right = slot L
    if (act) upd(Ae, Ce, Be, be, &S[L + 31][0], &S[L + 32][0]);
    __syncthreads();

    // ---------- 6 PCR levels on the 50-row system ----------
#pragma unroll
    for (int lv = 0; lv < 6; ++lv) {
        const int s = 1 << lv;  // 1,2,4,8,16,32
        if (act) {
            double P[9], Q[9], z[3];
            pqz(Ae, Ce, Be, be, P, Q, z);
            store21(&S[L + 32][0], P, Q, z);
        }
        __syncthreads();
        if (act) upd(Ae, Ce, Be, be, &S[L + 32 - s][0], &S[L + 32 + s][0]);
        __syncthreads();
    }

    // ---------- local solve (even rows), exchange x, recover odd rows ----------
    double xe[3] = {0.0, 0.0, 0.0};
    if (act) {
        double G[6];
        syminv3(Ae, G);
        symvec(G, be, xe);
        X[L + 1][0] = xe[0]; X[L + 1][1] = xe[1]; X[L + 1][2] = xe[2];
    }
    __syncthreads();

    if (act) {
        const double xr0 = X[L + 2][0], xr1 = X[L + 2][1], xr2 = X[L + 2][2];
        double xo[3];
#pragma unroll
        for (int r = 0; r < 3; ++r)
            xo[r] = zo[r]
                  - (Po[3 * r] * xe[0] + Po[3 * r + 1] * xe[1] + Po[3 * r + 2] * xe[2])
                  - (Qo[3 * r] * xr0   + Qo[3 * r + 1] * xr1   + Qo[3 * r + 2] * xr2);

        const int t0 = 2 * L, t1 = 2 * L + 1;
        out[            b * NSTEP + t0] = (float)xe[0];
        out[            b * NSTEP + t1] = (float)xo[0];
        out[25600 +     b * NSTEP + t0] = (float)xe[1];
        out[25600 +     b * NSTEP + t1] = (float)xo[1];
        out[51200 +     b * NSTEP + t0] = (float)xe[2];
        out[51200 +     b * NSTEP + t1] = (float)xo[2];
    }

    // eps + st copy (d_out poisoned every iteration)
    for (int t = L; t < T1; t += 64)
        out[77056 + b * T1 + t] = sb[t];
    if (L == 0)
        out[76800 + b] = 0.0f;
}

extern "C" void kernel_launch(void* const* d_in, const int* in_sizes, int n_in,
                              void* d_out, int out_size, void* d_ws, size_t ws_size,
                              hipStream_t stream) {
    const float* coeffs = (const float*)d_in[0];
    const float* rhs    = (const float*)d_in[1];
    const float* iv_rhs = (const float*)d_in[2];
    const float* steps  = (const float*)d_in[3];
    float* out = (float*)d_out;

    ode_pcr_kernel<<<dim3(NPROB), dim3(64), 0, stream>>>(
        coeffs, rhs, iv_rhs, steps, out);
}

// Round 6
// 65.132 us; speedup vs baseline: 2.4115x; 1.0270x over previous
//
#include <hip/hip_runtime.h>

// BS=32, N_IND=8 -> 256 problems; N_STEP=100, ORDER=2 -> 3x3 block-tridiagonal
// normal equations (verified R1-R5, absmax 0.0 in fp64).
// R6: CR(1)+PCR entirely in REGISTERS + WAVE SHUFFLES — no LDS, no barriers.
//   - one problem per wave64 (one WG per CU); rows live one-per-lane
//   - neighbor exchange (P,Q,z = 21 floats) via __shfl_up/__shfl_down
//   - boundary correctness: row 0's C block and row 49's B block are exactly
//     zero and remain zero through all PCR levels (C' = -C*P_l), so unmasked
//     out-of-range shfl data is always annihilated by zero matrices.
//   - fp32 throughout: threshold is 0.51 absolute; conditioning analysis says
//     fp32 lands ~1e-4..1e-2. fp64 fallback proven in R5 if this misses.
#define NPROB 256
#define NSTEP 100
#define T1    99

// A: symmetric 3x3 as [a00,a01,a02,a11,a12,a22]; C,B: row-major 3x3.
__device__ __forceinline__ void syminv3(const float A[6], float G[6]) {
    const float k00 = A[3] * A[5] - A[4] * A[4];
    const float k01 = A[2] * A[4] - A[1] * A[5];
    const float k02 = A[1] * A[4] - A[2] * A[3];
    const float det = A[0] * k00 + A[1] * k01 + A[2] * k02;
    const float id  = 1.0f / det;
    G[0] = k00 * id;
    G[1] = k01 * id;
    G[2] = k02 * id;
    G[3] = (A[0] * A[5] - A[2] * A[2]) * id;
    G[4] = (A[2] * A[1] - A[0] * A[4]) * id;
    G[5] = (A[0] * A[3] - A[1] * A[1]) * id;
}

__device__ __forceinline__ void symmul(const float G[6], const float M[9], float R[9]) {
#pragma unroll
    for (int c = 0; c < 3; ++c) {
        R[0 + c] = G[0] * M[c] + G[1] * M[3 + c] + G[2] * M[6 + c];
        R[3 + c] = G[1] * M[c] + G[3] * M[3 + c] + G[4] * M[6 + c];
        R[6 + c] = G[2] * M[c] + G[4] * M[3 + c] + G[5] * M[6 + c];
    }
}

__device__ __forceinline__ void symvec(const float G[6], const float v[3], float r[3]) {
    r[0] = G[0] * v[0] + G[1] * v[1] + G[2] * v[2];
    r[1] = G[1] * v[0] + G[3] * v[1] + G[4] * v[2];
    r[2] = G[2] * v[0] + G[4] * v[1] + G[5] * v[2];
}

// pub[21] = (P = A^-1 C, Q = A^-1 B, z = A^-1 b)
__device__ __forceinline__ void pqz(const float A[6], const float C[9],
                                    const float B[9], const float b[3], float pub[21]) {
    float G[6];
    syminv3(A, G);
    symmul(G, C, pub);       // P -> pub[0..8]
    symmul(G, B, pub + 9);   // Q -> pub[9..17]
    symvec(G, b, pub + 18);  // z -> pub[18..20]
}

// PCR/CR row update with neighbor data SL=(P,Q,z)_{left}, SR=(P,Q,z)_{right}:
//   A' = A - C*Q_l - B*P_r ; C' = -C*P_l ; B' = -B*Q_r ; b' = b - C*z_l - B*z_r
__device__ __forceinline__ void upd(float A[6], float C[9], float B[9], float b[3],
                                    const float SL[21], const float SR[21]) {
    const float* Pl = SL;      const float* Ql = SL + 9;  const float* zl = SL + 18;
    const float* Pr = SR;      const float* Qr = SR + 9;  const float* zr = SR + 18;

    const int RI[6] = {0, 0, 0, 1, 1, 2};
    const int CI[6] = {0, 1, 2, 1, 2, 2};
#pragma unroll
    for (int e = 0; e < 6; ++e) {
        const int r = RI[e], c = CI[e];
        A[e] -= C[3 * r] * Ql[c] + C[3 * r + 1] * Ql[3 + c] + C[3 * r + 2] * Ql[6 + c]
              + B[3 * r] * Pr[c] + B[3 * r + 1] * Pr[3 + c] + B[3 * r + 2] * Pr[6 + c];
    }
    float nC[9], nB[9];
#pragma unroll
    for (int r = 0; r < 3; ++r)
#pragma unroll
        for (int c = 0; c < 3; ++c) {
            nC[3 * r + c] = -(C[3 * r] * Pl[c] + C[3 * r + 1] * Pl[3 + c] + C[3 * r + 2] * Pl[6 + c]);
            nB[3 * r + c] = -(B[3 * r] * Qr[c] + B[3 * r + 1] * Qr[3 + c] + B[3 * r + 2] * Qr[6 + c]);
        }
#pragma unroll
    for (int r = 0; r < 3; ++r)
        b[r] -= C[3 * r] * zl[0] + C[3 * r + 1] * zl[1] + C[3 * r + 2] * zl[2]
              + B[3 * r] * zr[0] + B[3 * r + 1] * zr[1] + B[3 * r + 2] * zr[2];
#pragma unroll
    for (int k = 0; k < 9; ++k) { C[k] = nC[k]; B[k] = nB[k]; }
}

// Build block-row t of the normal equations (verified R1/R5).
__device__ __forceinline__ void build_row(int t, const float* cb, const float* rb,
                                          const float* sb, const float* ivp,
                                          float A[6], float C[9], float B[9], float b[3]) {
    const float c0 = cb[t * 3 + 0];
    const float c1 = cb[t * 3 + 1];
    const float c2 = cb[t * 3 + 2];
    const float r  = rb[t];
    A[0] = c0 * c0; A[1] = c0 * c1; A[2] = c0 * c2;
    A[3] = c1 * c1; A[4] = c1 * c2; A[5] = c2 * c2;
    b[0] = c0 * r;  b[1] = c1 * r;  b[2] = c2 * r;
#pragma unroll
    for (int k = 0; k < 9; ++k) { C[k] = 0.0f; B[k] = 0.0f; }

    if (t == 0) {
        A[0] += 1.0f; A[3] += 1.0f;
        b[0] += ivp[0];
        b[1] += ivp[1];
    }
    if (t < T1) {  // U(h_t); B = E(h_t)^T
        const float h = sb[t], h2 = h * h;
        A[0] += 2.0f;
        A[1] += h;
        A[2] += 0.5f * h2;
        A[3] += h2 + 3.0f;
        A[4] += 0.5f * h2 * h + 1.5f * h;
        A[5] += 0.25f * h2 * h2 + 1.25f * h2;
        B[0] = -2.0f;      B[1] =  h;        B[2] = -0.5f * h2;
        B[3] = -h;         B[4] = -3.0f;     B[5] =  1.5f * h;
        B[6] = -0.5f * h2; B[7] = -1.5f * h; B[8] =  0.25f * h2;
    }
    if (t > 0) {   // V(h_{t-1}); C = E(h_{t-1})
        const float hm = sb[t - 1], hm2 = hm * hm;
        A[0] += 2.0f;
        A[1] -= hm;
        A[2] += 0.5f * hm2;
        A[3] += hm2 + 3.0f;
        A[4] -= 0.5f * hm2 * hm + 1.5f * hm;
        A[5] += 0.25f * hm2 * hm2 + 1.25f * hm2;
        C[0] = -2.0f;      C[1] = -hm;       C[2] = -0.5f * hm2;
        C[3] =  hm;        C[4] = -3.0f;     C[5] = -1.5f * hm;
        C[6] = -0.5f * hm2; C[7] = 1.5f * hm; C[8] = 0.25f * hm2;
    }
}

__device__ __forceinline__ void shflup21(const float v[21], float o[21], int s) {
#pragma unroll
    for (int k = 0; k < 21; ++k) o[k] = __shfl_up(v[k], s, 64);
}
__device__ __forceinline__ void shfldn21(const float v[21], float o[21], int s) {
#pragma unroll
    for (int k = 0; k < 21; ++k) o[k] = __shfl_down(v[k], s, 64);
}

__global__ __launch_bounds__(64, 1) void ode_pcr_shfl_kernel(
    const float* __restrict__ coeffs,  // [256][100][3]
    const float* __restrict__ rhs,     // [256][100]
    const float* __restrict__ iv_rhs,  // [256][2]
    const float* __restrict__ steps,   // [256][99]
    float* __restrict__ out)           // u0[25600] u1[25600] u2[25600] eps[256] st[25344]
{
    const int b = blockIdx.x;
    const int L = threadIdx.x;
    const bool act = (L < 50);

    const float* cb  = coeffs + b * NSTEP * 3;
    const float* rb  = rhs    + b * NSTEP;
    const float* sb  = steps  + b * T1;
    const float* ivp = iv_rhs + b * 2;

    float Ae[6], Ce[9], Be[9], be[3];  // even row 2L of the 50-row system
    float pubo[21];                    // odd row 2L+1 publish data (kept for recovery)
#pragma unroll
    for (int k = 0; k < 21; ++k) pubo[k] = 0.0f;
#pragma unroll
    for (int k = 0; k < 6; ++k) Ae[k] = 0.0f;
#pragma unroll
    for (int k = 0; k < 9; ++k) { Ce[k] = 0.0f; Be[k] = 0.0f; }
    be[0] = be[1] = be[2] = 0.0f;

    // ---------- build + CR pre-step: fold odd rows into even rows ----------
    if (act) {
        build_row(2 * L, cb, rb, sb, ivp, Ae, Ce, Be, be);
        float Ao[6], Co[9], Bo[9], bo[3];
        build_row(2 * L + 1, cb, rb, sb, ivp, Ao, Co, Bo, bo);
        pqz(Ao, Co, Bo, bo, pubo);
    }
    {
        float SL[21];
        shflup21(pubo, SL, 1);         // lane L-1's odd pub; L==0: self, killed by Ce==0
        if (act) upd(Ae, Ce, Be, be, SL, pubo);
    }

    // ---------- 6 PCR levels on the 50-row system (s = 1..32) ----------
#pragma unroll
    for (int lv = 0; lv < 6; ++lv) {
        const int s = 1 << lv;
        float pub[21];
#pragma unroll
        for (int k = 0; k < 21; ++k) pub[k] = 0.0f;
        if (act) pqz(Ae, Ce, Be, be, pub);
        float SL[21], SR[21];
        shflup21(pub, SL, s);          // out-of-range -> self, killed by zero C block
        shfldn21(pub, SR, s);          // out-of-range -> self/zero-lane, killed by zero B
        if (act) upd(Ae, Ce, Be, be, SL, SR);
    }

    // ---------- local solve, x-exchange via shfl, odd-row recovery ----------
    float xe[3] = {0.0f, 0.0f, 0.0f};
    if (act) {
        float G[6];
        syminv3(Ae, G);
        symvec(G, be, xe);
    }
    float xr[3];
    xr[0] = __shfl_down(xe[0], 1, 64);
    xr[1] = __shfl_down(xe[1], 1, 64);
    xr[2] = __shfl_down(xe[2], 1, 64);  // L==49 reads lane 50: xe there is 0

    if (act) {
        const float* Po = pubo;
        const float* Qo = pubo + 9;
        const float* zo = pubo + 18;
        float xo[3];
#pragma unroll
        for (int r = 0; r < 3; ++r)
            xo[r] = zo[r]
                  - (Po[3 * r] * xe[0] + Po[3 * r + 1] * xe[1] + Po[3 * r + 2] * xe[2])
                  - (Qo[3 * r] * xr[0] + Qo[3 * r + 1] * xr[1] + Qo[3 * r + 2] * xr[2]);

        const int t0 = 2 * L, t1 = 2 * L + 1;
        out[            b * NSTEP + t0] = xe[0];
        out[            b * NSTEP + t1] = xo[0];
        out[25600 +     b * NSTEP + t0] = xe[1];
        out[25600 +     b * NSTEP + t1] = xo[1];
        out[51200 +     b * NSTEP + t0] = xe[2];
        out[51200 +     b * NSTEP + t1] = xo[2];
    }

    // eps + st copy (d_out is re-poisoned before every launch)
    for (int t = L; t < T1; t += 64)
        out[77056 + b * T1 + t] = sb[t];
    if (L == 0)
        out[76800 + b] = 0.0f;
}

extern "C" void kernel_launch(void* const* d_in, const int* in_sizes, int n_in,
                              void* d_out, int out_size, void* d_ws, size_t ws_size,
                              hipStream_t stream) {
    const float* coeffs = (const float*)d_in[0];
    const float* rhs    = (const float*)d_in[1];
    const float* iv_rhs = (const float*)d_in[2];
    const float* steps  = (const float*)d_in[3];
    float* out = (float*)d_out;

    ode_pcr_shfl_kernel<<<dim3(NPROB), dim3(64), 0, stream>>>(
        coeffs, rhs, iv_rhs, steps, out);
}